// Round 3
// baseline (814.829 us; speedup 1.0000x reference)
//
#include <hip/hip_runtime.h>

typedef __bf16 bf16x8 __attribute__((ext_vector_type(8)));
typedef float f32x4 __attribute__((ext_vector_type(4)));

__device__ __forceinline__ unsigned short f2bf(float f) {
    union { float f; unsigned int u; } x; x.f = f;
    unsigned int r = x.u + 0x7FFFu + ((x.u >> 16) & 1u);
    return (unsigned short)(r >> 16);
}
__device__ __forceinline__ float bf2f(unsigned short v) {
    union { unsigned int u; float f; } x; x.u = ((unsigned int)v) << 16; return x.f;
}

// ---------------- Kernel 0: pre-convert Wv1 [512x512] and Wv2 [256x512] to bf16
__global__ __launch_bounds__(256) void k_prep(
    const float* __restrict__ Wv1, const float* __restrict__ Wv2,
    unsigned short* __restrict__ Wv1bf, unsigned short* __restrict__ Wv2bf)
{
    int idx = blockIdx.x * 256 + threadIdx.x;
    if (idx < 262144) {
        Wv1bf[idx] = f2bf(Wv1[idx]);
    } else {
        int j = idx - 262144;           // < 131072
        Wv2bf[j] = f2bf(Wv2[j]);
    }
}

// ---------------- Kernel 1: aq1 = relu(af@Wa1^T+ba1), aq2 = relu(af@Wa2^T+ba2)
// af[bt,k] = audio[t,b,k], bt = b*10+t. 4 bt per block, 640 blocks.
__global__ __launch_bounds__(256) void k_audio(
    const float* __restrict__ audio,
    const float* __restrict__ Wa1, const float* __restrict__ ba1,
    const float* __restrict__ Wa2, const float* __restrict__ ba2,
    float* __restrict__ aq1, float* __restrict__ aq2)
{
    __shared__ float afs[4][128];
    const int btBase = blockIdx.x * 4;
    const int tid = threadIdx.x;
    for (int i = tid; i < 512; i += 256) {
        int g = i >> 7, k = i & 127;
        int bt = btBase + g;
        int b = bt / 10, t = bt - b * 10;
        afs[g][k] = audio[(t * 256 + b) * 128 + k];
    }
    __syncthreads();
    const int c = tid;  // 0..255
    float a1a[4] = {0.f,0.f,0.f,0.f}, a1b[4] = {0.f,0.f,0.f,0.f}, a2[4] = {0.f,0.f,0.f,0.f};
    const float* w1a = Wa1 + c * 128;
    const float* w1b = Wa1 + (c + 256) * 128;
    const float* w2p = Wa2 + c * 128;
    for (int kk = 0; kk < 32; ++kk) {
        float4 va = *(const float4*)(w1a + kk * 4);
        float4 vb = *(const float4*)(w1b + kk * 4);
        float4 vc = *(const float4*)(w2p + kk * 4);
        float fa[4] = {va.x, va.y, va.z, va.w};
        float fb[4] = {vb.x, vb.y, vb.z, vb.w};
        float fc[4] = {vc.x, vc.y, vc.z, vc.w};
#pragma unroll
        for (int j = 0; j < 4; ++j) {
            int k = kk * 4 + j;
#pragma unroll
            for (int g = 0; g < 4; ++g) {
                float a = afs[g][k];
                a1a[g] += a * fa[j];
                a1b[g] += a * fb[j];
                a2[g]  += a * fc[j];
            }
        }
    }
    float b1a = ba1[c], b1b = ba1[c + 256], b2 = ba2[c];
#pragma unroll
    for (int g = 0; g < 4; ++g) {
        int bt = btBase + g;
        aq1[bt * 512 + c]       = fmaxf(a1a[g] + b1a, 0.f);
        aq1[bt * 512 + c + 256] = fmaxf(a1b[g] + b1b, 0.f);
        aq2[bt * 256 + c]       = fmaxf(a2[g] + b2, 0.f);
    }
}

// ---------------- Kernel 2: avq[bt,n] = aq1[bt,n] * mean_hw relu(vf@Wv1^T + bv1)
// MFMA 16x16x32 bf16; M-tiles at rows {0,16,32,33}; row 48 deduped from tile 3 only.
__global__ __launch_bounds__(256) void k_chanatt(
    const float* __restrict__ video,
    const unsigned short* __restrict__ Wv1bf, const float* __restrict__ bv1,
    const float* __restrict__ aq1, float* __restrict__ avq)
{
    __shared__ unsigned short At[49 * 512];  // bf16, XOR chunk-swizzled
    const int bt = blockIdx.x;
    const int tid = threadIdx.x;
    const int wave = tid >> 6, lane = tid & 63, quad = lane >> 4, l16 = lane & 15;
    const float* vsrc = video + (size_t)bt * 25088;

    for (int c = tid; c < 3136; c += 256) {
        int row = c >> 6, ch = c & 63;
        float4 a = *(const float4*)(vsrc + row * 512 + ch * 8);
        float4 b = *(const float4*)(vsrc + row * 512 + ch * 8 + 4);
        float f[8] = {a.x, a.y, a.z, a.w, b.x, b.y, b.z, b.w};
        unsigned int o[8];
#pragma unroll
        for (int j = 0; j < 8; ++j) o[j] = f2bf(f[j]);
        uint4 pack;
        pack.x = o[0] | (o[1] << 16); pack.y = o[2] | (o[3] << 16);
        pack.z = o[4] | (o[5] << 16); pack.w = o[6] | (o[7] << 16);
        int chs = ch ^ (row & 7);
        *(uint4*)(&At[row * 512 + chs * 8]) = pack;
    }
    __syncthreads();

    f32x4 acc[4][8];
#pragma unroll
    for (int mt = 0; mt < 4; ++mt)
#pragma unroll
        for (int nt = 0; nt < 8; ++nt)
            acc[mt][nt] = (f32x4){0.f, 0.f, 0.f, 0.f};

    for (int kk = 0; kk < 16; ++kk) {
        int chunk = kk * 4 + quad;   // k-group of 8; koff = chunk*8
        bf16x8 afrag[4];
#pragma unroll
        for (int mt = 0; mt < 4; ++mt) {
            int m = ((mt == 3) ? 33 : mt * 16) + l16;
            int chs = chunk ^ (m & 7);
            afrag[mt] = *(const bf16x8*)(&At[m * 512 + chs * 8]);
        }
        int koff = chunk * 8;
#pragma unroll
        for (int nt = 0; nt < 8; ++nt) {
            int n = (wave * 8 + nt) * 16 + l16;
            bf16x8 bfrag = *(const bf16x8*)(Wv1bf + n * 512 + koff);
#pragma unroll
            for (int mt = 0; mt < 4; ++mt)
                acc[mt][nt] = __builtin_amdgcn_mfma_f32_16x16x32_bf16(
                    afrag[mt], bfrag, acc[mt][nt], 0, 0, 0);
        }
    }

#pragma unroll
    for (int nt = 0; nt < 8; ++nt) {
        int n = (wave * 8 + nt) * 16 + l16;
        float bias = bv1[n];
        float s = 0.f;
#pragma unroll
        for (int mt = 0; mt < 4; ++mt)
#pragma unroll
            for (int r = 0; r < 4; ++r)
                if (mt < 3 || (quad == 3 && r == 3))
                    s += fmaxf(acc[mt][nt][r] + bias, 0.f);
        s += __shfl_xor(s, 16, 64);
        s += __shfl_xor(s, 32, 64);
        if (quad == 0) {
            float vm = s * (1.f / 49.f);
            avq[bt * 512 + n] = aq1[bt * 512 + n] * vm;
        }
    }
}

// ---------------- Kernel 3: cmul = 1 + sigmoid( relu(avq@Wb^T+bb) @ Wc^T + bc )
__global__ __launch_bounds__(256) void k_mlp(
    const float* __restrict__ avq,
    const float* __restrict__ Wb, const float* __restrict__ bb,
    const float* __restrict__ Wc, const float* __restrict__ bc,
    float* __restrict__ cmul)
{
    __shared__ float av[4][512];
    __shared__ float hid[4][256];
    const int btBase = blockIdx.x * 4;
    const int tid = threadIdx.x;
    for (int i = tid; i < 2048; i += 256) {
        int g = i >> 9, c = i & 511;
        av[g][c] = avq[(btBase + g) * 512 + c];
    }
    __syncthreads();
    {
        float a[4] = {0.f,0.f,0.f,0.f};
        const float* wrow = Wb + tid * 512;
        for (int kk = 0; kk < 128; ++kk) {
            float4 v = *(const float4*)(wrow + kk * 4);
            float w[4] = {v.x, v.y, v.z, v.w};
#pragma unroll
            for (int j = 0; j < 4; ++j)
#pragma unroll
                for (int g = 0; g < 4; ++g)
                    a[g] += av[g][kk * 4 + j] * w[j];
        }
        float bias = bb[tid];
#pragma unroll
        for (int g = 0; g < 4; ++g) hid[g][tid] = fmaxf(a[g] + bias, 0.f);
    }
    __syncthreads();
#pragma unroll
    for (int rep = 0; rep < 2; ++rep) {
        int c = tid + rep * 256;
        float a[4] = {0.f,0.f,0.f,0.f};
        const float* wrow = Wc + c * 256;
        for (int kk = 0; kk < 64; ++kk) {
            float4 v = *(const float4*)(wrow + kk * 4);
            float w[4] = {v.x, v.y, v.z, v.w};
#pragma unroll
            for (int j = 0; j < 4; ++j)
#pragma unroll
                for (int g = 0; g < 4; ++g)
                    a[g] += hid[g][kk * 4 + j] * w[j];
        }
        float bias = bc[c];
#pragma unroll
        for (int g = 0; g < 4; ++g) {
            float s = 1.f / (1.f + __expf(-(a[g] + bias)));
            cmul[(btBase + g) * 512 + c] = 1.f + s;
        }
    }
}

// ---------------- Kernel 4: spatial attention + output, per bt
__global__ __launch_bounds__(256) void k_spatial(
    const float* __restrict__ video,
    const float* __restrict__ cmul, const float* __restrict__ aq2,
    const unsigned short* __restrict__ Wv2bf, const float* __restrict__ bv2,
    const float* __restrict__ Wsp, const float* __restrict__ bsp,
    float* __restrict__ out)
{
    __shared__ unsigned short Ct[49 * 512];  // c_att bf16, XOR chunk-swizzled
    __shared__ float w2[256];
    __shared__ float zbuf[4][64];
    __shared__ float smw[64];
    const int bt = blockIdx.x;
    const int tid = threadIdx.x;
    const int wave = tid >> 6, lane = tid & 63, quad = lane >> 4, l16 = lane & 15;
    const float* vsrc = video + (size_t)bt * 25088;
    const float* cm = cmul + bt * 512;

    for (int c = tid; c < 3136; c += 256) {
        int row = c >> 6, ch = c & 63;
        float4 a = *(const float4*)(vsrc + row * 512 + ch * 8);
        float4 b = *(const float4*)(vsrc + row * 512 + ch * 8 + 4);
        float f[8] = {a.x, a.y, a.z, a.w, b.x, b.y, b.z, b.w};
        float4 m0 = *(const float4*)(cm + ch * 8);
        float4 m1 = *(const float4*)(cm + ch * 8 + 4);
        float mm[8] = {m0.x, m0.y, m0.z, m0.w, m1.x, m1.y, m1.z, m1.w};
        unsigned int o[8];
#pragma unroll
        for (int j = 0; j < 8; ++j) o[j] = f2bf(f[j] * mm[j]);
        uint4 pack;
        pack.x = o[0] | (o[1] << 16); pack.y = o[2] | (o[3] << 16);
        pack.z = o[4] | (o[5] << 16); pack.w = o[6] | (o[7] << 16);
        int chs = ch ^ (row & 7);
        *(uint4*)(&Ct[row * 512 + chs * 8]) = pack;
    }
    w2[tid] = aq2[bt * 256 + tid] * Wsp[tid];
    if (lane >= 49) zbuf[wave][lane] = 0.f;   // rows 49..63 never written below
    __syncthreads();

    f32x4 acc[4][4];
#pragma unroll
    for (int mt = 0; mt < 4; ++mt)
#pragma unroll
        for (int nt = 0; nt < 4; ++nt)
            acc[mt][nt] = (f32x4){0.f, 0.f, 0.f, 0.f};

    for (int kk = 0; kk < 16; ++kk) {
        int chunk = kk * 4 + quad;
        bf16x8 afrag[4];
#pragma unroll
        for (int mt = 0; mt < 4; ++mt) {
            int m = ((mt == 3) ? 33 : mt * 16) + l16;
            int chs = chunk ^ (m & 7);
            afrag[mt] = *(const bf16x8*)(&Ct[m * 512 + chs * 8]);
        }
        int koff = chunk * 8;
#pragma unroll
        for (int nt = 0; nt < 4; ++nt) {
            int n = (wave * 4 + nt) * 16 + l16;
            bf16x8 bfrag = *(const bf16x8*)(Wv2bf + n * 512 + koff);
#pragma unroll
            for (int mt = 0; mt < 4; ++mt)
                acc[mt][nt] = __builtin_amdgcn_mfma_f32_16x16x32_bf16(
                    afrag[mt], bfrag, acc[mt][nt], 0, 0, 0);
        }
    }

    // zp[mt*4+r] = sum over this wave's 64 cols of relu(cq + bias) * aq2 * Ws
    float zp[16];
#pragma unroll
    for (int i = 0; i < 16; ++i) zp[i] = 0.f;
#pragma unroll
    for (int nt = 0; nt < 4; ++nt) {
        int n = (wave * 4 + nt) * 16 + l16;
        float bias = bv2[n];
        float wn = w2[n];
#pragma unroll
        for (int mt = 0; mt < 4; ++mt)
#pragma unroll
            for (int r = 0; r < 4; ++r)
                zp[mt * 4 + r] += fmaxf(acc[mt][nt][r] + bias, 0.f) * wn;
    }
#pragma unroll
    for (int i = 0; i < 16; ++i) {
        float v = zp[i];
        v += __shfl_xor(v, 1, 64);
        v += __shfl_xor(v, 2, 64);
        v += __shfl_xor(v, 4, 64);
        v += __shfl_xor(v, 8, 64);
        zp[i] = v;
    }
    if (l16 == 0) {
#pragma unroll
        for (int mt = 0; mt < 4; ++mt)
#pragma unroll
            for (int r = 0; r < 4; ++r)
                if (mt < 3 || (quad == 3 && r == 3)) {
                    int row = ((mt == 3) ? 33 : mt * 16) + quad * 4 + r;
                    zbuf[wave][row] = zp[mt * 4 + r];
                }
    }
    __syncthreads();

    if (wave == 0) {
        int hw = lane;
        float z = zbuf[0][hw] + zbuf[1][hw] + zbuf[2][hw] + zbuf[3][hw] + bsp[0];
        float t = tanhf(z);
        float v = (hw < 49) ? t : -1e30f;
#pragma unroll
        for (int off = 32; off; off >>= 1) v = fmaxf(v, __shfl_xor(v, off, 64));
        float e = (hw < 49) ? __expf(t - v) : 0.f;
        float se = e;
#pragma unroll
        for (int off = 32; off; off >>= 1) se += __shfl_xor(se, off, 64);
        smw[hw] = e / se;
    }
    __syncthreads();

#pragma unroll
    for (int rep = 0; rep < 2; ++rep) {
        int cidx = tid + rep * 256;
        int chb = cidx >> 3, jj = cidx & 7;
        float s = 0.f;
        for (int hw = 0; hw < 49; ++hw) {
            int chs = chb ^ (hw & 7);
            s += smw[hw] * bf2f(Ct[hw * 512 + chs * 8 + jj]);
        }
        out[bt * 512 + cidx] = s;
    }
}

extern "C" void kernel_launch(void* const* d_in, const int* in_sizes, int n_in,
                              void* d_out, int out_size, void* d_ws, size_t ws_size,
                              hipStream_t stream) {
    const float* video = (const float*)d_in[0];
    const float* audio = (const float*)d_in[1];
    const float* Wv1 = (const float*)d_in[2];
    const float* bv1 = (const float*)d_in[3];
    const float* Wa1 = (const float*)d_in[4];
    const float* ba1 = (const float*)d_in[5];
    const float* Wb  = (const float*)d_in[6];
    const float* bb  = (const float*)d_in[7];
    const float* Wc  = (const float*)d_in[8];
    const float* bc  = (const float*)d_in[9];
    const float* Wv2 = (const float*)d_in[10];
    const float* bv2 = (const float*)d_in[11];
    const float* Wa2 = (const float*)d_in[12];
    const float* ba2 = (const float*)d_in[13];
    const float* Wsp = (const float*)d_in[14];
    const float* bsp = (const float*)d_in[15];

    float* ws = (float*)d_ws;
    float* aq1  = ws;                       // [2560,512]
    float* aq2  = aq1 + 1310720;            // [2560,256]
    float* avq  = aq2 + 655360;             // [2560,512]
    float* cmul = avq + 1310720;            // [2560,512]
    unsigned short* Wv1bf = (unsigned short*)(cmul + 1310720);  // 512x512
    unsigned short* Wv2bf = Wv1bf + 262144;                     // 256x512
    float* out = (float*)d_out;

    k_prep<<<1536, 256, 0, stream>>>(Wv1, Wv2, Wv1bf, Wv2bf);
    k_audio<<<640, 256, 0, stream>>>(audio, Wa1, ba1, Wa2, ba2, aq1, aq2);
    k_chanatt<<<2560, 256, 0, stream>>>(video, Wv1bf, bv1, aq1, avq);
    k_mlp<<<640, 256, 0, stream>>>(avq, Wb, bb, Wc, bc, cmul);
    k_spatial<<<2560, 256, 0, stream>>>(video, cmul, aq2, Wv2bf, bv2, Wsp, bsp, out);
}